// Round 2
// baseline (2702.778 us; speedup 1.0000x reference)
//
#include <hip/hip_runtime.h>
#include <hip/hip_bf16.h>

typedef __attribute__((ext_vector_type(8))) short short8;
typedef __attribute__((ext_vector_type(4))) float f32x4;

#define TWARM 96
#define SOUT  24

__device__ __forceinline__ float fsig(float x) {
    // sigmoid(x) = 1 / (1 + 2^(-x*log2e))
    float e = __builtin_amdgcn_exp2f(-1.44269504089f * x);
    return __builtin_amdgcn_rcpf(1.0f + e);
}
__device__ __forceinline__ float ftanh(float x) {
    // tanh(x) = 2 / (1 + 2^(-2x*log2e)) - 1
    float e = __builtin_amdgcn_exp2f(-2.88539008178f * x);
    return fmaf(2.0f, __builtin_amdgcn_rcpf(1.0f + e), -1.0f);
}
__device__ __forceinline__ short f2bf(float f) {
    __hip_bfloat16 h = __float2bfloat16(f);
    return *reinterpret_cast<short*>(&h);
}

// One wave owns 16 batch rows for the whole sequence (rows are independent).
// Per step: Z[16][256] = x@W + b + H[16][64] @ U[64][256] via 32 MFMAs,
// gates in-register, h transposed through a padded per-wave LDS buffer.
// NO inline asm: the only fence is one __syncthreads() per step.
__global__ void __launch_bounds__(256, 2)
lstm_ar_kernel(const float* __restrict__ gin, const float* __restrict__ gW,
               const float* __restrict__ gU, const float* __restrict__ gb,
               const float* __restrict__ gWd, const float* __restrict__ gbd,
               float* __restrict__ gout, int B)
{
    // U as pre-swizzled bf16 B-fragments: frag(n,kk): lane l holds
    // U[k = kk*32 + (l>>4)*8 + e][col = 16n + (l&15)], e contiguous -> ds_read_b128
    __shared__ __align__(16) short U_lds[16384];            // 32 KB
    __shared__ __align__(16) short h_lds[4][16][72];        // per-wave, 144B row stride (pad 8)

    const int tid  = threadIdx.x;
    const int wv   = tid >> 6;
    const int lane = tid & 63;
    const int c4   = lane & 15;   // MFMA col / A-row selector
    const int hi   = lane >> 4;   // MFMA k-group / C-row group

    // ---- stage U (coalesced global read, swizzled LDS write) ----
    for (int idx = tid; idx < 16384; idx += 256) {
        int k = idx >> 8, col = idx & 255;
        int dst = (((col >> 4) * 2 + (k >> 5)) * 4 + ((k & 31) >> 3)) * 128
                + (col & 15) * 8 + (k & 7);
        U_lds[dst] = f2bf(gU[idx]);
    }

    // ---- per-lane constants: W row0/row1, bias for this lane's 16 cols ----
    float W0c[16], W1c[16], bc[16];
#pragma unroll
    for (int n = 0; n < 16; ++n) {
        int col = n * 16 + c4;
        W0c[n] = gW[col];
        W1c[n] = gW[256 + col];
        bc[n]  = gb[col];
    }
    float wdc[4][2];
#pragma unroll
    for (int tt = 0; tt < 4; ++tt) {
        wdc[tt][0] = gWd[(tt * 16 + c4) * 2 + 0];
        wdc[tt][1] = gWd[(tt * 16 + c4) * 2 + 1];
    }
    const float bd0 = gbd[0], bd1 = gbd[1];

    const int row0   = blockIdx.x * 64 + wv * 16;
    const bool active = (row0 + 15) < B;   // whole-wave row validity (grid fits B exactly)

    // zero this wave's h buffer
    for (int i = lane; i < 16 * 72; i += 64) (&h_lds[wv][0][0])[i] = 0;
    __syncthreads();   // U staged + h zeroed

    f32x4 acc[16];
    float c_[4][4], h_[4][4];
#pragma unroll
    for (int tt = 0; tt < 4; ++tt)
#pragma unroll
        for (int r = 0; r < 4; ++r) { c_[tt][r] = 0.f; h_[tt][r] = 0.f; }

    const short* hptr  = &h_lds[wv][0][0] + c4 * 72 + hi * 8;          // A-frag read base
    short*       hwptr = &h_lds[wv][0][0] + (hi * 4) * 72 + c4;        // h write base
    const short* uptr  = U_lds + lane * 8;                             // B-frag read base

#pragma unroll 1
    for (int t = 0; t < TWARM + SOUT; ++t) {
        float x0[4], x1[4];
        if (t < TWARM) {
#pragma unroll
            for (int r = 0; r < 4; ++r) {
                float2 xv = make_float2(0.f, 0.f);
                if (active)
                    xv = *reinterpret_cast<const float2*>(
                        gin + ((size_t)(row0 + hi * 4 + r) * TWARM + t) * 2);
                x0[r] = xv.x; x1[r] = xv.y;
            }
        } else {
            // pred = h @ Wd + bd ; butterfly reduce over the 16-lane col group
            // leaves the bit-identical sum in EVERY lane -> no LDS broadcast needed.
            const int s = t - TWARM;
            float p0[4], p1[4];
#pragma unroll
            for (int r = 0; r < 4; ++r) {
                float a0 = 0.f, a1 = 0.f;
#pragma unroll
                for (int tt = 0; tt < 4; ++tt) {
                    a0 = fmaf(h_[tt][r], wdc[tt][0], a0);
                    a1 = fmaf(h_[tt][r], wdc[tt][1], a1);
                }
                p0[r] = a0; p1[r] = a1;
            }
#pragma unroll
            for (int m = 1; m < 16; m <<= 1) {
#pragma unroll
                for (int r = 0; r < 4; ++r) {
                    p0[r] += __shfl_xor(p0[r], m, 64);
                    p1[r] += __shfl_xor(p1[r], m, 64);
                }
            }
#pragma unroll
            for (int r = 0; r < 4; ++r) { p0[r] += bd0; p1[r] += bd1; }
            if (active && c4 == 0) {
#pragma unroll
                for (int r = 0; r < 4; ++r) {
                    *reinterpret_cast<float2*>(
                        gout + ((size_t)(row0 + hi * 4 + r) * SOUT + s) * 2) =
                        make_float2(p0[r], p1[r]);
                }
            }
            if (t == TWARM + SOUT - 1) break;   // uniform across all waves; no barrier after
#pragma unroll
            for (int r = 0; r < 4; ++r) { x0[r] = p0[r]; x1[r] = p1[r]; }
        }

        // ---- acc init: b + x@W (rank-2 update as MFMA C-in) ----
#pragma unroll
        for (int n = 0; n < 16; ++n)
#pragma unroll
            for (int r = 0; r < 4; ++r)
                acc[n][r] = fmaf(x1[r], W1c[n], fmaf(x0[r], W0c[n], bc[n]));

        // ---- Z += H @ U ----  (h_lds writes of step t-1 fenced by the barrier below)
        short8 a0 = *reinterpret_cast<const short8*>(hptr);
        short8 a1 = *reinterpret_cast<const short8*>(hptr + 32);
#pragma unroll
        for (int n = 0; n < 16; ++n) {
            short8 u0 = *reinterpret_cast<const short8*>(uptr + (n * 2 + 0) * 512);
            short8 u1 = *reinterpret_cast<const short8*>(uptr + (n * 2 + 1) * 512);
            acc[n] = __builtin_amdgcn_mfma_f32_16x16x32_bf16(a0, u0, acc[n], 0, 0, 0);
            acc[n] = __builtin_amdgcn_mfma_f32_16x16x32_bf16(a1, u1, acc[n], 0, 0, 0);
        }

        // ---- gates: tiles [i | f | g | o] at n = tt, tt+4, tt+8, tt+12 ----
#pragma unroll
        for (int tt = 0; tt < 4; ++tt) {
#pragma unroll
            for (int r = 0; r < 4; ++r) {
                float zi = acc[tt][r];
                float zf = acc[tt + 4][r];
                float zg = acc[tt + 8][r];
                float zo = acc[tt + 12][r];
                float si = fsig(zi);
                float sf = fsig(zf);
                float so = fsig(zo);
                float tg = ftanh(zg);
                float cn = fmaf(sf, c_[tt][r], si * tg);
                c_[tt][r] = cn;
                float hn = so * ftanh(cn);
                h_[tt][r] = hn;
                hwptr[r * 72 + tt * 16] = f2bf(hn);   // h -> LDS (transpose for next A-frag)
            }
        }
        __syncthreads();   // canonical fence: h writes complete before next step's reads
    }
}

extern "C" void kernel_launch(void* const* d_in, const int* in_sizes, int n_in,
                              void* d_out, int out_size, void* d_ws, size_t ws_size,
                              hipStream_t stream) {
    const float* gin  = (const float*)d_in[0];
    const float* gW   = (const float*)d_in[1];
    const float* gU   = (const float*)d_in[2];
    const float* gb   = (const float*)d_in[3];
    const float* gWd  = (const float*)d_in[4];
    const float* gbd  = (const float*)d_in[5];
    float* gout = (float*)d_out;

    const int B = in_sizes[0] / (TWARM * 2);
    const int blocks = (B + 63) / 64;
    lstm_ar_kernel<<<blocks, 256, 0, stream>>>(gin, gW, gU, gb, gWd, gbd, gout, B);
}

// Round 3
// 1481.398 us; speedup vs baseline: 1.8245x; 1.8245x over previous
//
#include <hip/hip_runtime.h>
#include <hip/hip_bf16.h>
#include <hip/hip_fp16.h>

typedef __attribute__((ext_vector_type(8))) short short8;
typedef __attribute__((ext_vector_type(4))) float f32x4;

#define TWARM 96
#define SOUT  24
#define WIN   48   // x staging window (timesteps per LDS window)

__device__ __forceinline__ float fsig(float x) {
    float e = __builtin_amdgcn_exp2f(-1.44269504089f * x);
    return __builtin_amdgcn_rcpf(1.0f + e);
}
__device__ __forceinline__ float ftanh(float x) {
    float e = __builtin_amdgcn_exp2f(-2.88539008178f * x);
    return fmaf(2.0f, __builtin_amdgcn_rcpf(1.0f + e), -1.0f);
}
__device__ __forceinline__ short f2bf(float f) {
    __hip_bfloat16 h = __float2bfloat16(f);
    return *reinterpret_cast<short*>(&h);
}

// One wave owns 16 batch rows for the whole 119-step sequence.
// Per step: Z[16][256] = x@W + b + H[16][64]@U[64][256] via 32 MFMAs, gates
// in-register, h transposed through a padded per-wave LDS buffer.
// x is staged block-cooperatively into LDS (fp16, two 48-step windows) so the
// recurrence never touches HBM. No inline asm; one __syncthreads per step.
__global__ void __launch_bounds__(256, 2)
lstm_ar_kernel(const float* __restrict__ gin, const float* __restrict__ gW,
               const float* __restrict__ gU, const float* __restrict__ gb,
               const float* __restrict__ gWd, const float* __restrict__ gbd,
               float* __restrict__ gout, int B)
{
    __shared__ __align__(16) short  U_lds[16384];           // 32 KB, pre-swizzled B-frags
    __shared__ __align__(16) short  h_lds[4][16][72];       // 9 KB, per-wave padded
    __shared__ __align__(16) __half x_lds[64][2 * WIN + 2]; // 12.25 KB, 98 halves/row

    const int tid  = threadIdx.x;
    const int wv   = tid >> 6;
    const int lane = tid & 63;
    const int c4   = lane & 15;   // MFMA col / A-row selector
    const int hi   = lane >> 4;   // MFMA k-group / C-row group

    // ---- stage U (coalesced global read, swizzled LDS write) ----
    for (int idx = tid; idx < 16384; idx += 256) {
        int k = idx >> 8, col = idx & 255;
        int dst = (((col >> 4) * 2 + (k >> 5)) * 4 + ((k & 31) >> 3)) * 128
                + (col & 15) * 8 + (k & 7);
        U_lds[dst] = f2bf(gU[idx]);
    }

    // ---- per-lane constants ----
    float W0c[16], W1c[16], bc[16];
#pragma unroll
    for (int n = 0; n < 16; ++n) {
        int col = n * 16 + c4;
        W0c[n] = gW[col];
        W1c[n] = gW[256 + col];
        bc[n]  = gb[col];
    }
    float wdc[4][2];
#pragma unroll
    for (int tt = 0; tt < 4; ++tt) {
        wdc[tt][0] = gWd[(tt * 16 + c4) * 2 + 0];
        wdc[tt][1] = gWd[(tt * 16 + c4) * 2 + 1];
    }
    const float bd0 = gbd[0], bd1 = gbd[1];

    const int rowblk = blockIdx.x * 64;
    const int row0   = rowblk + wv * 16;
    const bool active = (row0 + 15) < B;

    // zero this wave's h buffer
    for (int i = lane; i < 16 * 72; i += 64) (&h_lds[wv][0][0])[i] = 0;

    // ---- block-cooperative x window staging (coalesced, fp16 convert) ----
    const int srow = tid >> 2, sq = tid & 3;    // 4 threads per row, 24 floats each
    auto stage_x = [&](int w) {
        const float* src = gin + (size_t)(rowblk + srow) * (TWARM * 2)
                         + w * (WIN * 2) + sq * 24;
        const bool ok = (rowblk + srow) < B;
#pragma unroll
        for (int m = 0; m < 6; ++m) {
            float4 v = ok ? *reinterpret_cast<const float4*>(src + m * 4)
                          : make_float4(0.f, 0.f, 0.f, 0.f);
            int kk = sq * 24 + m * 4;           // local float idx, 4-aligned
            __half2* dst = reinterpret_cast<__half2*>(&x_lds[srow][kk]);
            dst[0] = __floats2half2_rn(v.x, v.y);
            dst[1] = __floats2half2_rn(v.z, v.w);
        }
    };

    stage_x(0);
    __syncthreads();   // U + h-zero + x window 0 all visible

    float c_[4][4], h_[4][4];
#pragma unroll
    for (int tt = 0; tt < 4; ++tt)
#pragma unroll
        for (int r = 0; r < 4; ++r) { c_[tt][r] = 0.f; h_[tt][r] = 0.f; }

    const short* hptr  = &h_lds[wv][0][0] + c4 * 72 + hi * 8;     // A-frag read base
    short*       hwptr = &h_lds[wv][0][0] + (hi * 4) * 72 + c4;   // h write base
    const short* uptr  = U_lds + lane * 8;                        // B-frag read base
    const __half2* xw  = reinterpret_cast<const __half2*>(&x_lds[0][0]);
    const int xbase    = (wv * 16 + hi * 4) * 49;                 // half2-word base

    // ---- one LSTM step: Z = x@W + b + H@U ; gates ; h -> LDS ; barrier ----
    auto lstm_step = [&](const float* x0, const float* x1) {
        f32x4 acc[16];
#pragma unroll
        for (int n = 0; n < 16; ++n)
#pragma unroll
            for (int r = 0; r < 4; ++r)
                acc[n][r] = fmaf(x1[r], W1c[n], fmaf(x0[r], W0c[n], bc[n]));

        short8 a0 = *reinterpret_cast<const short8*>(hptr);
        short8 a1 = *reinterpret_cast<const short8*>(hptr + 32);
#pragma unroll
        for (int n = 0; n < 16; ++n) {
            short8 u0 = *reinterpret_cast<const short8*>(uptr + (n * 2 + 0) * 512);
            short8 u1 = *reinterpret_cast<const short8*>(uptr + (n * 2 + 1) * 512);
            acc[n] = __builtin_amdgcn_mfma_f32_16x16x32_bf16(a0, u0, acc[n], 0, 0, 0);
            acc[n] = __builtin_amdgcn_mfma_f32_16x16x32_bf16(a1, u1, acc[n], 0, 0, 0);
        }

#pragma unroll
        for (int tt = 0; tt < 4; ++tt)
#pragma unroll
            for (int r = 0; r < 4; ++r) {
                float zi = acc[tt][r];
                float zf = acc[tt + 4][r];
                float zg = acc[tt + 8][r];
                float zo = acc[tt + 12][r];
                float si = fsig(zi);
                float sf = fsig(zf);
                float so = fsig(zo);
                float tg = ftanh(zg);
                float cn = fmaf(sf, c_[tt][r], si * tg);
                c_[tt][r] = cn;
                float hn = so * ftanh(cn);
                h_[tt][r] = hn;
                hwptr[r * 72 + tt * 16] = f2bf(hn);
            }
        __syncthreads();
    };

    // ---- warmup: 96 steps, x from LDS windows ----
#pragma unroll 1
    for (int w = 0; w < TWARM / WIN; ++w) {
        if (w != 0) {
            stage_x(w);       // previous step's barrier fenced all window reads
            __syncthreads();  // staging visible before first read
        }
#pragma unroll 1
        for (int tl = 0; tl < WIN; ++tl) {
            float x0[4], x1[4];
#pragma unroll
            for (int r = 0; r < 4; ++r) {
                float2 xf = __half22float2(xw[xbase + r * 49 + tl]);
                x0[r] = xf.x; x1[r] = xf.y;
            }
            lstm_step(x0, x1);
        }
    }

    // ---- decode: pred = h@Wd + bd, butterfly over the 16-lane col group ----
    auto make_pred = [&](float* p0, float* p1) {
#pragma unroll
        for (int r = 0; r < 4; ++r) {
            float a0 = 0.f, a1 = 0.f;
#pragma unroll
            for (int tt = 0; tt < 4; ++tt) {
                a0 = fmaf(h_[tt][r], wdc[tt][0], a0);
                a1 = fmaf(h_[tt][r], wdc[tt][1], a1);
            }
            p0[r] = a0; p1[r] = a1;
        }
#pragma unroll
        for (int m = 1; m < 16; m <<= 1)
#pragma unroll
            for (int r = 0; r < 4; ++r) {
                p0[r] += __shfl_xor(p0[r], m, 64);
                p1[r] += __shfl_xor(p1[r], m, 64);
            }
#pragma unroll
        for (int r = 0; r < 4; ++r) { p0[r] += bd0; p1[r] += bd1; }
    };
    auto store_pred = [&](int s, const float* p0, const float* p1) {
        if (active && c4 == 0) {
#pragma unroll
            for (int r = 0; r < 4; ++r)
                *reinterpret_cast<float2*>(
                    gout + ((size_t)(row0 + hi * 4 + r) * SOUT + s) * 2) =
                    make_float2(p0[r], p1[r]);
        }
    };

    float p0[4], p1[4];
    make_pred(p0, p1);
    store_pred(0, p0, p1);
#pragma unroll 1
    for (int s = 1; s < SOUT; ++s) {
        lstm_step(p0, p1);
        make_pred(p0, p1);
        store_pred(s, p0, p1);
    }
}

extern "C" void kernel_launch(void* const* d_in, const int* in_sizes, int n_in,
                              void* d_out, int out_size, void* d_ws, size_t ws_size,
                              hipStream_t stream) {
    const float* gin  = (const float*)d_in[0];
    const float* gW   = (const float*)d_in[1];
    const float* gU   = (const float*)d_in[2];
    const float* gb   = (const float*)d_in[3];
    const float* gWd  = (const float*)d_in[4];
    const float* gbd  = (const float*)d_in[5];
    float* gout = (float*)d_out;

    const int B = in_sizes[0] / (TWARM * 2);
    const int blocks = (B + 63) / 64;
    lstm_ar_kernel<<<blocks, 256, 0, stream>>>(gin, gW, gU, gb, gWd, gbd, gout, B);
}